// Round 11
// baseline (332.370 us; speedup 1.0000x reference)
//
#include <hip/hip_runtime.h>
#include <cstddef>

#define NPTS 32768
#define DDIM 128
#define KCB  1024

typedef __attribute__((ext_vector_type(8))) short short8;  // 8 bf16 (4 VGPRs)
typedef __attribute__((ext_vector_type(4))) float f32x4;

// ---------- numeric helpers ----------

__device__ __forceinline__ float hw_exp2(float x) {
#if __has_builtin(__builtin_amdgcn_exp2f)
  return __builtin_amdgcn_exp2f(x);
#else
  return exp2f(x);
#endif
}

__device__ __forceinline__ void atomic_add_f64(double* p, double v) {
  __hip_atomic_fetch_add(p, v, __ATOMIC_RELAXED, __HIP_MEMORY_SCOPE_AGENT);
}

// bf16 round-to-nearest-even of a finite f32 (bit trick; no inf/nan here)
__device__ __forceinline__ unsigned short bf16_rne(float v) {
  unsigned u = __float_as_uint(v);
  unsigned r = u + 0x7FFFu + ((u >> 16) & 1u);
  return (unsigned short)(r >> 16);
}
__device__ __forceinline__ float bf16_tof(unsigned short h) {
  return __uint_as_float((unsigned)h << 16);
}

// correctly-rounded f32 division via 2-FMA Markstein refinement (rc = RN(1/c));
// bit-identical to IEEE '/' given correctly-rounded rc.
__device__ __forceinline__ float div_mark(float x, float c, float rc) {
  float q0 = x * rc;
  float r  = fmaf(-c, q0, x);
  return fmaf(r, rc, q0);
}

// E = exp(-dc/eps) with f64 range, rel err ~8e-8 (errors average out in the
// Sinkhorn row/col sums; NOT used for the final argmax score).
__device__ __forceinline__ double sweep_E(float cv, float middle, float amp, float rc_amp) {
  float d  = div_mark(1.0f - cv, 0.2f, 1.0f / 0.2f);
  float dc = div_mark(d - middle, amp, rc_amp);
  double xl2 = (double)dc * (-288.53900817779268);  // 200*log2(e)
  double kd  = rint(xl2);
  float  fr  = (float)(xl2 - kd);
  float  m   = hw_exp2(fr);
  long long bits = ((long long)(1023 + (int)kd)) << 52;
  return (double)m * __longlong_as_double(bits);
}

// f32 per-element ops matching jnp, for the exact-recheck score exponent
__device__ __forceinline__ double score_exponent(float cv, float middle, float amplitude) {
  float d  = (1.0f - cv) / 0.2f;
  float dc = (d - middle) / amplitude;
  return (double)dc * (-(1.0 / 0.005));
}

// order-preserving f32 <-> u32 encode for atomic min/max
__device__ __forceinline__ unsigned enc_f32(float f) {
  unsigned u = __float_as_uint(f);
  return (u & 0x80000000u) ? ~u : (u | 0x80000000u);
}
__device__ __forceinline__ float dec_f32(unsigned e) {
  unsigned u = (e & 0x80000000u) ? (e & 0x7FFFFFFFu) : ~e;
  return __uint_as_float(u);
}

// shared scalarization: middle / amplitude / rc from the encoded cos max/min.
// Pure f32 function of (maxenc,minenc) -> identical values in every block.
__device__ __forceinline__ void calc_scal(const unsigned* maxenc, const unsigned* minenc,
                                          float& middle, float& amplitude, float& rc_amp) {
  float cosmax = dec_f32(*maxenc);
  float cosmin = dec_f32(*minenc);
  float mx_d = (1.0f - cosmin) / 0.2f;
  float mn_d = (1.0f - cosmax) / 0.2f;
  middle = (mx_d + mn_d) / 2.0f;
  amplitude = fmaxf(mx_d - middle + 1e-5f, 1e-5f);
  rc_amp = 1.0f / amplitude;
}

// alpha = 1/max(sum(u1),1e-5), replicated BIT-EXACTLY from the retired
// finalize_u mode-0 reduction, but with a 256-thread block (4 waves):
// each wave computes 4 of the 16 per-64-block shfl_down tree sums (same
// tree order over the same 64 inputs as the original 16-wave version),
// then thread 0 does the same serial 16-term sum.  sred must be LDS[17].
__device__ __forceinline__ double calc_alpha_256(const double* __restrict__ u1,
                                                 double* sred) {
  int t = threadIdx.x, lane = t & 63, wv = t >> 6;
#pragma unroll
  for (int j = 0; j < 4; ++j) {
    int wb = wv * 4 + j;
    double s = u1[wb * 64 + lane];
#pragma unroll
    for (int off = 32; off; off >>= 1) s += __shfl_down(s, off, 64);
    if (lane == 0) sred[wb] = s;
  }
  __syncthreads();
  if (t == 0) {
    double s0 = 0.0;
    for (int w = 0; w < 16; ++w) s0 += sred[w];
    sred[16] = 1.0 / fmax(s0, 1e-5);
  }
  __syncthreads();
  return sred[16];
}

// async global->LDS 16B: per-lane gptr, WAVE-UNIFORM lds base, lane lands at +lane*16
#if __has_builtin(__builtin_amdgcn_global_load_lds)
#define HAVE_ASYNC_LDS 1
typedef __attribute__((address_space(3))) unsigned int lds_u32_t;
typedef const __attribute__((address_space(1))) unsigned int glb_u32_t;
__device__ __forceinline__ void async_ld16(const void* g, void* l) {
  __builtin_amdgcn_global_load_lds((glb_u32_t*)g, (lds_u32_t*)l, 16, 0, 0);
}
#else
#define HAVE_ASYNC_LDS 0
#endif

// raw sync primitives for the counted-vmcnt pipeline (T3/T4 template)
#define WAITVM8() asm volatile("s_waitcnt vmcnt(8)" ::: "memory")
#define WAITVM4() asm volatile("s_waitcnt vmcnt(4)" ::: "memory")
#define WAITVM0() asm volatile("s_waitcnt vmcnt(0)" ::: "memory")
#define CFENCE()  asm volatile("" ::: "memory")
#define SBAR()    do { CFENCE(); __builtin_amdgcn_s_barrier(); CFENCE(); } while (0)

// ---------- kernels ----------

// L2-normalize rows, emit split bf16 planes: v = hi + lo + O(2^-18 v).
// R9: workspace init fused into block 0 (init pointers non-null).
__global__ __launch_bounds__(128) void vq_normalize_split(const float* __restrict__ in,
                                                          unsigned short* __restrict__ oh,
                                                          unsigned short* __restrict__ ol,
                                                          double* __restrict__ init_u123,
                                                          double* __restrict__ init_loss,
                                                          unsigned* __restrict__ maxenc,
                                                          unsigned* __restrict__ minenc) {
  int row = blockIdx.x;
  int t = threadIdx.x;
  if (init_u123 != nullptr && row == 0) {
    for (int i = t; i < 3 * KCB; i += 128) init_u123[i] = 0.0;
    for (int i = t; i < KCB; i += 128) init_loss[i] = 0.0;
    if (t == 0) {
      *maxenc = 0u;
      *minenc = 0xFFFFFFFFu;
    }
  }
  float v = in[(size_t)row * DDIM + t];
  float s = v * v;
#pragma unroll
  for (int off = 32; off; off >>= 1) s += __shfl_down(s, off, 64);
  __shared__ float red[2];
  if ((t & 63) == 0) red[t >> 6] = s;
  __syncthreads();
  float norm = sqrtf(red[0] + red[1]);
  float xnv = v / fmaxf(norm, 1e-12f);
  unsigned short h = bf16_rne(xnv);
  float fh = bf16_tof(h);
  unsigned short l = bf16_rne(xnv - fh);  // v - fh exact in f32
  size_t idx = (size_t)row * DDIM + t;
  oh[idx] = h;
  ol[idx] = l;
}

// L2-normalize rows of BOTH x and cb in one launch (R9).
__global__ __launch_bounds__(128) void vq_normalize_rows2(const float* __restrict__ xin,
                                                          const float* __restrict__ cbin,
                                                          float* __restrict__ xout,
                                                          float* __restrict__ cbout) {
  int b = blockIdx.x;
  const float* in;
  float* out;
  size_t row;
  if (b < NPTS) { in = xin; out = xout; row = b; }
  else          { in = cbin; out = cbout; row = b - NPTS; }
  int t = threadIdx.x;
  float v = in[row * DDIM + t];
  float s = v * v;
#pragma unroll
  for (int off = 32; off; off >>= 1) s += __shfl_down(s, off, 64);
  __shared__ float red[2];
  if ((t & 63) == 0) red[t >> 6] = s;
  __syncthreads();
  float norm = sqrtf(red[0] + red[1]);
  out[row * DDIM + t] = v / fmaxf(norm, 1e-12f);
}

// ---- MFMA GEMM: cos = A·B^T, 2-way bf16 split, m201-ported 8-phase template.
// UNCHANGED (R5/R8 structure).  Structure ledger (totals; per-dispatch rocprof
// cross-run noise is +-25%): R2 fine-split slow; R6 small tile = +10us total;
// R5 2-phase == R7 merged within total-noise; keeping 2-phase.
// Virtual-K: K' = 512, chunk t = 4*ks + j; A-plane = (j<2?hi:lo),
// B-plane = (j&1?lo:hi); t ascending == baseline hh,hl,lh,ll per ks ->
// per-acc accumulation order unchanged -> Cm BIT-IDENTICAL.

__global__ __launch_bounds__(512, 2) void vq_gemm_mfma(const unsigned short* __restrict__ Ah,
                                                       const unsigned short* __restrict__ Al,
                                                       const unsigned short* __restrict__ Bh,
                                                       const unsigned short* __restrict__ Bl,
                                                       float* __restrict__ Cm,
                                                       unsigned* __restrict__ maxenc,
                                                       unsigned* __restrict__ minenc) {
  __shared__ unsigned short Ab[4][8192];  // 4 x 16KB: [256 rows][32 k] swizzled
  __shared__ unsigned short Bb[4][8192];  // 4 x 16KB
  __shared__ float redmx[8], redmn[8];
  int tid = threadIdx.x;
  int lane = tid & 63, wv = tid >> 6;
  int wm = wv >> 2, wn = wv & 3;          // wave tile: rows wm*128, cols wn*64
  int n0 = blockIdx.x * 256;              // x = row-block: consecutive blocks share B panel
  int c0 = blockIdx.y * 256;
  int fr = lane & 15;
  // swizzled 16B slot for frag reads: j' = (lane>>4) ^ ((fr>>1)&3), in shorts
  int swz8 = (((lane >> 4) ^ ((lane >> 1) & 3))) * 8;
  int arow = (wm * 128 + fr) * 32 + swz8;  // shorts into A buffer (+rt*512)
  int brow = (wn * 64 + fr) * 32 + swz8;   // shorts into B buffer (+ct*512)
  // stage source swizzle (involution of the read swizzle), constant per thread
  int srcj8 = (((tid & 3) ^ ((tid >> 3) & 3))) * 8;
  int r0 = tid >> 2;                       // staged row for chunk l=0
  f32x4 acc[8][4] = {};                    // [rt][ct]

  auto stageA = [&](int t) {
    const unsigned short* p = ((t & 3) < 2) ? Ah : Al;
    const unsigned short* g = p + (size_t)(n0 + r0) * DDIM + (t >> 2) * 32 + srcj8;
    unsigned short* lb = &Ab[t & 3][wv * 512];  // wave-uniform; lane at +lane*16B
#if HAVE_ASYNC_LDS
    async_ld16(g, lb);
    async_ld16(g + (size_t)128 * DDIM, lb + 4096);
#else
    *(short8*)(&Ab[t & 3][tid * 8])        = *(const short8*)g;
    *(short8*)(&Ab[t & 3][4096 + tid * 8]) = *(const short8*)(g + (size_t)128 * DDIM);
#endif
  };
  auto stageB = [&](int t) {
    const unsigned short* p = (t & 1) ? Bl : Bh;
    const unsigned short* g = p + (size_t)(c0 + r0) * DDIM + (t >> 2) * 32 + srcj8;
    unsigned short* lb = &Bb[t & 3][wv * 512];
#if HAVE_ASYNC_LDS
    async_ld16(g, lb);
    async_ld16(g + (size_t)128 * DDIM, lb + 4096);
#else
    *(short8*)(&Bb[t & 3][tid * 8])        = *(const short8*)g;
    *(short8*)(&Bb[t & 3][4096 + tid * 8]) = *(const short8*)(g + (size_t)128 * DDIM);
#endif
  };

  // prologue: stage K-steps 0,1,2 (12 vm instr/wave); require step 0 done.
  stageA(0); stageB(0);
  stageA(1); stageB(1);
  stageA(2); stageB(2);
  WAITVM8();
  SBAR();

  short8 af[4], bf[4];
#pragma unroll
  for (int t = 0; t < 16; ++t) {
    const unsigned short* ab = &Ab[t & 3][0];
    const unsigned short* bb = &Bb[t & 3][0];
    // ---------- phase 1: B(ct0-3) + A(rt0-3) frags; stage A-unit of t+3
#pragma unroll
    for (int ct = 0; ct < 4; ++ct) bf[ct] = *(const short8*)(bb + brow + ct * 512);
#pragma unroll
    for (int rt = 0; rt < 4; ++rt) af[rt] = *(const short8*)(ab + arow + rt * 512);
    if (t <= 12) stageA(t + 3);
    SBAR();
    __builtin_amdgcn_s_setprio(1);
#pragma unroll
    for (int rt = 0; rt < 4; ++rt)
#pragma unroll
      for (int ct = 0; ct < 4; ++ct)
        acc[rt][ct] = __builtin_amdgcn_mfma_f32_16x16x32_bf16(af[rt], bf[ct], acc[rt][ct], 0, 0, 0);
    __builtin_amdgcn_s_setprio(0);
    SBAR();
    // ---------- phase 2: A(rt4-7) frags; stage B-unit of t+3
#pragma unroll
    for (int rt = 0; rt < 4; ++rt) af[rt] = *(const short8*)(ab + arow + (rt + 4) * 512);
    if (t <= 12) stageB(t + 3);
    SBAR();
    __builtin_amdgcn_s_setprio(1);
#pragma unroll
    for (int rt = 0; rt < 4; ++rt)
#pragma unroll
      for (int ct = 0; ct < 4; ++ct)
        acc[rt + 4][ct] = __builtin_amdgcn_mfma_f32_16x16x32_bf16(af[rt], bf[ct], acc[rt + 4][ct], 0, 0, 0);
    __builtin_amdgcn_s_setprio(0);
    // K-step boundary: ensure buf (t+1) staged chip-wide before next reads.
    if (t <= 12) WAITVM8();
    else if (t == 13) WAITVM4();
    else if (t == 14) WAITVM0();
    SBAR();
  }

  float mx = -3.402823466e38f, mn = 3.402823466e38f;
  int orow = (lane >> 4) * 4, ocol = lane & 15;
  int rn0 = n0 + wm * 128, rc0 = c0 + wn * 64;
#pragma unroll
  for (int rt = 0; rt < 8; ++rt) {
#pragma unroll
    for (int ct = 0; ct < 4; ++ct) {
#pragma unroll
      for (int r = 0; r < 4; ++r) {
        float v = acc[rt][ct][r];
        mx = fmaxf(mx, v);
        mn = fminf(mn, v);
        Cm[(size_t)(rn0 + rt * 16 + orow + r) * KCB + (rc0 + ct * 16 + ocol)] = v;
      }
    }
  }
#pragma unroll
  for (int off = 32; off; off >>= 1) {
    mx = fmaxf(mx, __shfl_down(mx, off, 64));
    mn = fminf(mn, __shfl_down(mn, off, 64));
  }
  if (lane == 0) { redmx[wv] = mx; redmn[wv] = mn; }
  __syncthreads();
  if (tid == 0) {
#pragma unroll
    for (int w = 1; w < 8; ++w) {
      mx = fmaxf(mx, redmx[w]);
      mn = fminf(mn, redmn[w]);
    }
    mx = fmaxf(mx, redmx[0]);
    mn = fminf(mn, redmn[0]);
    atomicMax(maxenc, enc_f32(mx));
    atomicMin(minenc, enc_f32(mn));
  }
}

// ---- Sinkhorn sweep: wave-per-row, zero per-row barriers, depth-1 prefetch.
// R9: in-block bit-exact alpha/R recomputation (calc_alpha_256). ----
#define SROWS 32
#define SRPW  8

__global__ __launch_bounds__(256) void vq_sweep(const float* __restrict__ Cm,
                                                const unsigned* __restrict__ maxenc,
                                                const unsigned* __restrict__ minenc,
                                                const double* __restrict__ u_alpha,
                                                const double* __restrict__ u_prev,
                                                double* __restrict__ u_out) {
  int t = threadIdx.x;
  int lane = t & 63, wv = t >> 6;
  int n0 = blockIdx.x * SROWS + wv * SRPW;
  float middle, amp, rc;
  calc_scal(maxenc, minenc, middle, amp, rc);
  __shared__ double su[4][KCB];  // 32 KB
  __shared__ double sred[17];
  bool hasR = (u_prev != nullptr);
  double Rreg[16];
  double ainv = 0.0;
  if (hasR) {
    double alpha = calc_alpha_256(u_alpha, sred);
#pragma unroll
    for (int c = 0; c < 4; ++c)
#pragma unroll
      for (int e = 0; e < 4; ++e)
        Rreg[c * 4 + e] = 1.0 / (alpha * 1024.0 * u_prev[c * 256 + lane * 4 + e]);
    ainv = alpha * 32768.0;
  }
  double up[16] = {};
  float4 cva[4], cvb[4];
  {
    const float4* row0 = (const float4*)(Cm + (size_t)n0 * KCB);
#pragma unroll
    for (int c = 0; c < 4; ++c) cva[c] = row0[c * 64 + lane];
  }
#pragma unroll 1
  for (int r = 0; r < SRPW; ++r) {
    int rn = (r < SRPW - 1) ? r + 1 : r;
    const float4* rown = (const float4*)(Cm + (size_t)(n0 + rn) * KCB);
#pragma unroll
    for (int c = 0; c < 4; ++c) cvb[c] = rown[c * 64 + lane];
    double e[16];
#pragma unroll
    for (int c = 0; c < 4; ++c) {
      e[c * 4 + 0] = sweep_E(cva[c].x, middle, amp, rc);
      e[c * 4 + 1] = sweep_E(cva[c].y, middle, amp, rc);
      e[c * 4 + 2] = sweep_E(cva[c].z, middle, amp, rc);
      e[c * 4 + 3] = sweep_E(cva[c].w, middle, amp, rc);
    }
    if (hasR) {
      double s = 0.0;
#pragma unroll
      for (int i = 0; i < 16; ++i) s += e[i] * Rreg[i];
#pragma unroll
      for (int off = 1; off < 64; off <<= 1) s += __shfl_xor(s, off, 64);
      double C = 1.0 / (ainv * s);
#pragma unroll
      for (int i = 0; i < 16; ++i) up[i] += e[i] * C;
    } else {
#pragma unroll
      for (int i = 0; i < 16; ++i) up[i] += e[i];
    }
#pragma unroll
    for (int c = 0; c < 4; ++c) cva[c] = cvb[c];
  }
#pragma unroll
  for (int c = 0; c < 4; ++c)
#pragma unroll
    for (int e = 0; e < 4; ++e) su[wv][c * 256 + lane * 4 + e] = up[c * 4 + e];
  __syncthreads();
#pragma unroll
  for (int j = 0; j < 4; ++j) {
    int k = (t + ((blockIdx.x + j) & 3) * 256) & (KCB - 1);
    double v = su[0][k] + su[1][k] + su[2][k] + su[3][k];
    atomic_add_f64(&u_out[k], v);
  }
}

// ---- final pass: wave-per-row; f32 top-2 argmax with exact-recheck, CE loss.
// R11: ROW-PAIR INTERLEAVE.  Diagnosis (R3/R10 counters: VALUBusy ~50%,
// MfmaUtil 0, HBM ~16%, dur tracks clock not code): the wave spends ~half
// its cycles stalled on the two 6-step shfl_xor butterfly chains per row
// (each step's shuffles depend on the previous step).  Fix: process rows
// in independent PAIRS (A=r, B=r+1); each row's own op sequence (scores,
// shfl order, se summation, loss add order A-then-B == r-then-r+1) is
// textually unchanged -> bit-identical; only cross-row instruction
// interleaving changes, so row B's shuffles hide row A's latency.
// sv/lv stay fully-unrolled static-indexed (rule #20).  cvb prefetch
// dropped (pair loads at head serve the same overlap role). ----
#define FRPW 4
#define MARGIN 0.08f
#define LOG2E 1.44269504088896340736f

__global__ __launch_bounds__(256) void vq_final_pass(const float* __restrict__ Cm,
                                                     const float* __restrict__ x,
                                                     const float* __restrict__ cb,
                                                     const float* __restrict__ xn,
                                                     const float* __restrict__ cn,
                                                     const double* __restrict__ u1p,
                                                     const double* __restrict__ u3p,
                                                     const unsigned* __restrict__ maxenc,
                                                     const unsigned* __restrict__ minenc,
                                                     double* __restrict__ loss_part,
                                                     float* __restrict__ out_xq,
                                                     float* __restrict__ out_idx) {
  int t = threadIdx.x;
  int lane = t & 63, wv = t >> 6;
  int n0 = blockIdx.x * (4 * FRPW) + wv * FRPW;
  float middle, amplitude, rc_amp;
  calc_scal(maxenc, minenc, middle, amplitude, rc_amp);
  __shared__ double sred[17];
  __shared__ double lnRs[KCB];  // 8 KB
  {
    double alpha = calc_alpha_256(u1p, sred);
    for (int i = t; i < KCB; i += 256)
      lnRs[i] = log(1.0 / (alpha * 1024.0 * u3p[i]));
    __syncthreads();
  }
  float lnRf[16];
#pragma unroll
  for (int c = 0; c < 4; ++c)
#pragma unroll
    for (int e = 0; e < 4; ++e)
      lnRf[c * 4 + e] = (float)lnRs[c * 256 + lane * 4 + e];

  double loss_loc = 0.0;
#pragma unroll 1
  for (int r = 0; r < FRPW; r += 2) {
    int nA = n0 + r, nB = n0 + r + 1;
    float4 cvA[4], cvB[4];
    {
      const float4* rowA = (const float4*)(Cm + (size_t)nA * KCB);
      const float4* rowB = (const float4*)(Cm + (size_t)nB * KCB);
#pragma unroll
      for (int c = 0; c < 4; ++c) cvA[c] = rowA[c * 64 + lane];
#pragma unroll
      for (int c = 0; c < 4; ++c) cvB[c] = rowB[c * 64 + lane];
    }

    float lvA[16], svA[16], lvB[16], svB[16];
    float b1A = -3.402823466e38f, b2A = -3.402823466e38f, lmaxA = -3.402823466e38f;
    float b1B = -3.402823466e38f, b2B = -3.402823466e38f, lmaxB = -3.402823466e38f;
    int k1A = 0, k1B = 0;
    // scores row A (op order identical to the single-row version)
#pragma unroll
    for (int c = 0; c < 4; ++c) {
#pragma unroll
      for (int e = 0; e < 4; ++e) {
        float cvv = (e == 0) ? cvA[c].x : (e == 1) ? cvA[c].y : (e == 2) ? cvA[c].z : cvA[c].w;
        int k = c * 256 + lane * 4 + e;
        float d  = div_mark(1.0f - cvv, 0.2f, 5.0f);
        float dc = div_mark(d - middle, amplitude, rc_amp);
        float s  = fmaf(dc, -200.0f, lnRf[c * 4 + e]);
        svA[c * 4 + e] = s;
        if (s > b1A) { b2A = b1A; b1A = s; k1A = k; }
        else if (s > b2A) b2A = s;
        float l = div_mark(cvv, 0.2f, 5.0f);
        lvA[c * 4 + e] = l;
        lmaxA = fmaxf(lmaxA, l);
      }
    }
    // scores row B
#pragma unroll
    for (int c = 0; c < 4; ++c) {
#pragma unroll
      for (int e = 0; e < 4; ++e) {
        float cvv = (e == 0) ? cvB[c].x : (e == 1) ? cvB[c].y : (e == 2) ? cvB[c].z : cvB[c].w;
        int k = c * 256 + lane * 4 + e;
        float d  = div_mark(1.0f - cvv, 0.2f, 5.0f);
        float dc = div_mark(d - middle, amplitude, rc_amp);
        float s  = fmaf(dc, -200.0f, lnRf[c * 4 + e]);
        svB[c * 4 + e] = s;
        if (s > b1B) { b2B = b1B; b1B = s; k1B = k; }
        else if (s > b2B) b2B = s;
        float l = div_mark(cvv, 0.2f, 5.0f);
        lvB[c * 4 + e] = l;
        lmaxB = fmaxf(lmaxB, l);
      }
    }
    // interleaved butterflies: per-row shfl/update sequence unchanged;
    // the two rows' chains are independent -> B's shuffles hide A's latency
#pragma unroll
    for (int off = 1; off < 64; off <<= 1) {
      float o1A = __shfl_xor(b1A, off, 64);
      int okA = __shfl_xor(k1A, off, 64);
      float o2A = __shfl_xor(b2A, off, 64);
      float omA = __shfl_xor(lmaxA, off, 64);
      float o1B = __shfl_xor(b1B, off, 64);
      int okB = __shfl_xor(k1B, off, 64);
      float o2B = __shfl_xor(b2B, off, 64);
      float omB = __shfl_xor(lmaxB, off, 64);
      float cand2A;
      if (o1A > b1A || (o1A == b1A && okA < k1A)) { cand2A = fmaxf(b1A, o2A); b1A = o1A; k1A = okA; }
      else cand2A = fmaxf(o1A, o2A);
      b2A = fmaxf(b2A, cand2A);
      lmaxA = fmaxf(lmaxA, omA);
      float cand2B;
      if (o1B > b1B || (o1B == b1B && okB < k1B)) { cand2B = fmaxf(b1B, o2B); b1B = o1B; k1B = okB; }
      else cand2B = fmaxf(o1B, o2B);
      b2B = fmaxf(b2B, cand2B);
      lmaxB = fmaxf(lmaxB, omB);
    }
    int bestkA = k1A, bestkB = k1B;
    if (b1A - b2A < MARGIN) {
      double pbest = -1.0e308;
      int pk = KCB;
      const float4* xr4 = (const float4*)(xn + (size_t)nA * DDIM);
      float thr = b1A - MARGIN;
#pragma unroll
      for (int i = 0; i < 16; ++i) {
        if (svA[i] >= thr) {
          int k = (i >> 2) * 256 + lane * 4 + (i & 3);
          const float4* cr4 = (const float4*)(cn + (size_t)k * DDIM);
          float dot = 0.0f;
#pragma unroll 4
          for (int d = 0; d < DDIM / 4; ++d) {
            float4 xv4 = xr4[d];
            float4 cv4 = cr4[d];
            dot = fmaf(xv4.x, cv4.x, dot);
            dot = fmaf(xv4.y, cv4.y, dot);
            dot = fmaf(xv4.z, cv4.z, dot);
            dot = fmaf(xv4.w, cv4.w, dot);
          }
          double ps = score_exponent(dot, middle, amplitude) + lnRs[k];
          if (ps > pbest || (ps == pbest && k < pk)) { pbest = ps; pk = k; }
        }
      }
#pragma unroll
      for (int off = 1; off < 64; off <<= 1) {
        double ob = __shfl_xor(pbest, off, 64);
        int ok = __shfl_xor(pk, off, 64);
        if (ob > pbest || (ob == pbest && ok < pk)) { pbest = ob; pk = ok; }
      }
      bestkA = pk;
    }
    if (b1B - b2B < MARGIN) {
      double pbest = -1.0e308;
      int pk = KCB;
      const float4* xr4 = (const float4*)(xn + (size_t)nB * DDIM);
      float thr = b1B - MARGIN;
#pragma unroll
      for (int i = 0; i < 16; ++i) {
        if (svB[i] >= thr) {
          int k = (i >> 2) * 256 + lane * 4 + (i & 3);
          const float4* cr4 = (const float4*)(cn + (size_t)k * DDIM);
          float dot = 0.0f;
#pragma unroll 4
          for (int d = 0; d < DDIM / 4; ++d) {
            float4 xv4 = xr4[d];
            float4 cv4 = cr4[d];
            dot = fmaf(xv4.x, cv4.x, dot);
            dot = fmaf(xv4.y, cv4.y, dot);
            dot = fmaf(xv4.z, cv4.z, dot);
            dot = fmaf(xv4.w, cv4.w, dot);
          }
          double ps = score_exponent(dot, middle, amplitude) + lnRs[k];
          if (ps > pbest || (ps == pbest && k < pk)) { pbest = ps; pk = k; }
        }
      }
#pragma unroll
      for (int off = 1; off < 64; off <<= 1) {
        double ob = __shfl_xor(pbest, off, 64);
        int ok = __shfl_xor(pk, off, 64);
        if (ob > pbest || (ob == pbest && ok < pk)) { pbest = ob; pk = ok; }
      }
      bestkB = pk;
    }
    // sum exp (f32, fused exp2) + extract l[bestk], both rows; per-row
    // accumulation order unchanged; butterflies interleaved
    float seA = 0.0f, lbA = 0.0f, seB = 0.0f, lbB = 0.0f;
#pragma unroll
    for (int c = 0; c < 4; ++c) {
#pragma unroll
      for (int e = 0; e < 4; ++e) {
        int k = c * 256 + lane * 4 + e;
        seA += hw_exp2((lvA[c * 4 + e] - lmaxA) * LOG2E);
        if (k == bestkA) lbA = lvA[c * 4 + e];
      }
    }
#pragma unroll
    for (int c = 0; c < 4; ++c) {
#pragma unroll
      for (int e = 0; e < 4; ++e) {
        int k = c * 256 + lane * 4 + e;
        seB += hw_exp2((lvB[c * 4 + e] - lmaxB) * LOG2E);
        if (k == bestkB) lbB = lvB[c * 4 + e];
      }
    }
#pragma unroll
    for (int off = 1; off < 64; off <<= 1) {
      seA += __shfl_xor(seA, off, 64);
      lbA += __shfl_xor(lbA, off, 64);
      seB += __shfl_xor(seB, off, 64);
      lbB += __shfl_xor(lbB, off, 64);
    }
    loss_loc += (double)(-(lbA - lmaxA - logf(seA)));  // row r first,
    loss_loc += (double)(-(lbB - lmaxB - logf(seB)));  // then r+1: same order
    if (lane == 0) out_idx[nA] = (float)bestkA;
    {
      float2 xv = *(const float2*)&x[(size_t)nA * DDIM + lane * 2];
      float2 cbv = *(const float2*)&cb[(size_t)bestkA * DDIM + lane * 2];
      float2 o;
      o.x = xv.x + (cbv.x - xv.x);
      o.y = xv.y + (cbv.y - xv.y);
      *(float2*)&out_xq[(size_t)nA * DDIM + lane * 2] = o;
    }
    if (lane == 0) out_idx[nB] = (float)bestkB;
    {
      float2 xv = *(const float2*)&x[(size_t)nB * DDIM + lane * 2];
      float2 cbv = *(const float2*)&cb[(size_t)bestkB * DDIM + lane * 2];
      float2 o;
      o.x = xv.x + (cbv.x - xv.x);
      o.y = xv.y + (cbv.y - xv.y);
      *(float2*)&out_xq[(size_t)nB * DDIM + lane * 2] = o;
    }
  }
  if (lane == 0) atomic_add_f64(&loss_part[(blockIdx.x * 4 + wv) & (KCB - 1)], loss_loc);
}

__global__ __launch_bounds__(1024) void vq_loss_div(const double* __restrict__ lp,
                                                    float* __restrict__ out_loss) {
  int t = threadIdx.x;
  double s = lp[t];
#pragma unroll
  for (int off = 32; off; off >>= 1) s += __shfl_down(s, off, 64);
  __shared__ double red[16];
  if ((t & 63) == 0) red[t >> 6] = s;
  __syncthreads();
  if (t == 0) {
    double tot = 0.0;
    for (int w = 0; w < 16; ++w) tot += red[w];
    out_loss[0] = (float)(tot / 32768.0);
  }
}

// ---------- launch ----------
// R9 launch chain: 9 dispatches -- init fused into split(cb), normalize_rows
// merged, finalize_u eliminated via in-block bit-exact recomputation.

extern "C" void kernel_launch(void* const* d_in, const int* in_sizes, int n_in,
                              void* d_out, int out_size, void* d_ws, size_t ws_size,
                              hipStream_t stream) {
  const float* x  = (const float*)d_in[0];
  const float* cb = (const float*)d_in[1];
  float* out = (float*)d_out;
  float* out_xq   = out;
  float* out_loss = out + (size_t)NPTS * DDIM;
  float* out_idx  = out + (size_t)NPTS * DDIM + 1;

  // workspace layout (~144.6 MB):
  // [0, 16.5MB): phase 1 = bf16 planes (xh 8M, xl 8M, ch 256K, cl 256K)
  //              phase 2 (post-GEMM) = xn f32 16M, cn f32 512K  (overlay)
  char* w = (char*)d_ws;
  unsigned short* xh = (unsigned short*)w;                         // N*D bf16
  unsigned short* xl = xh + (size_t)NPTS * DDIM;                   // N*D bf16
  unsigned short* ch = xl + (size_t)NPTS * DDIM;                   // K*D bf16
  unsigned short* cl = ch + (size_t)KCB * DDIM;                    // K*D bf16
  float* xn = (float*)w;                                           // N*D f32 (overlay)
  float* cn = xn + (size_t)NPTS * DDIM;                            // K*D f32 (overlay)
  float* cosm = (float*)(w + (size_t)16896 * 1024);                // N*K f32 at +16.5MB
  double* u1  = (double*)(cosm + (size_t)NPTS * KCB);
  double* u2  = u1 + KCB;
  double* u3  = u2 + KCB;
  double* loss_part = u3 + KCB;                    // 1024
  unsigned* maxenc = (unsigned*)(loss_part + KCB);
  unsigned* minenc = maxenc + 1;

  // phase 1: split-normalized bf16 planes (cb-split block 0 also inits
  // u1/u2/u3/loss_part/maxenc/minenc) -> MFMA GEMM (8-phase template)
  vq_normalize_split<<<NPTS, 128, 0, stream>>>(x, xh, xl, nullptr, nullptr, nullptr, nullptr);
  vq_normalize_split<<<KCB, 128, 0, stream>>>(cb, ch, cl, u1, loss_part, maxenc, minenc);
  vq_gemm_mfma<<<dim3(NPTS / 256, KCB / 256), 512, 0, stream>>>(xh, xl, ch, cl, cosm,
                                                                maxenc, minenc);

  // phase 2: f32 normalized copies (overwrite plane region) for the recheck path
  vq_normalize_rows2<<<NPTS + KCB, 128, 0, stream>>>(x, cb, xn, cn);

  // Sinkhorn: u1 ; u2 (R1 from u1, in-block) ; u3 (R2 from u2, in-block)
  vq_sweep<<<NPTS / SROWS, 256, 0, stream>>>(cosm, maxenc, minenc, nullptr, nullptr, u1);
  vq_sweep<<<NPTS / SROWS, 256, 0, stream>>>(cosm, maxenc, minenc, u1, u1, u2);
  vq_sweep<<<NPTS / SROWS, 256, 0, stream>>>(cosm, maxenc, minenc, u1, u2, u3);

  // final pass computes lnR3 in-block from u1 (alpha) + u3
  vq_final_pass<<<NPTS / (4 * FRPW), 256, 0, stream>>>(cosm, x, cb, xn, cn, u1, u3,
                                                       maxenc, minenc,
                                                       loss_part, out_xq, out_idx);
  vq_loss_div<<<1, 1024, 0, stream>>>(loss_part, out_loss);
}

// Round 12
// 303.696 us; speedup vs baseline: 1.0944x; 1.0944x over previous
//
#include <hip/hip_runtime.h>
#include <cstddef>

#define NPTS 32768
#define DDIM 128
#define KCB  1024

typedef __attribute__((ext_vector_type(8))) short short8;  // 8 bf16 (4 VGPRs)
typedef __attribute__((ext_vector_type(4))) float f32x4;

// ---------- numeric helpers ----------

__device__ __forceinline__ float hw_exp2(float x) {
#if __has_builtin(__builtin_amdgcn_exp2f)
  return __builtin_amdgcn_exp2f(x);
#else
  return exp2f(x);
#endif
}

__device__ __forceinline__ void atomic_add_f64(double* p, double v) {
  __hip_atomic_fetch_add(p, v, __ATOMIC_RELAXED, __HIP_MEMORY_SCOPE_AGENT);
}

// bf16 round-to-nearest-even of a finite f32 (bit trick; no inf/nan here)
__device__ __forceinline__ unsigned short bf16_rne(float v) {
  unsigned u = __float_as_uint(v);
  unsigned r = u + 0x7FFFu + ((u >> 16) & 1u);
  return (unsigned short)(r >> 16);
}
__device__ __forceinline__ float bf16_tof(unsigned short h) {
  return __uint_as_float((unsigned)h << 16);
}

// correctly-rounded f32 division via 2-FMA Markstein refinement (rc = RN(1/c));
// bit-identical to IEEE '/' given correctly-rounded rc.
__device__ __forceinline__ float div_mark(float x, float c, float rc) {
  float q0 = x * rc;
  float r  = fmaf(-c, q0, x);
  return fmaf(r, rc, q0);
}

// E = exp(-dc/eps) with f64 range, rel err ~8e-8 (errors average out in the
// Sinkhorn row/col sums; NOT used for the final argmax score).
__device__ __forceinline__ double sweep_E(float cv, float middle, float amp, float rc_amp) {
  float d  = div_mark(1.0f - cv, 0.2f, 1.0f / 0.2f);
  float dc = div_mark(d - middle, amp, rc_amp);
  double xl2 = (double)dc * (-288.53900817779268);  // 200*log2(e)
  double kd  = rint(xl2);
  float  fr  = (float)(xl2 - kd);
  float  m   = hw_exp2(fr);
  long long bits = ((long long)(1023 + (int)kd)) << 52;
  return (double)m * __longlong_as_double(bits);
}

// f32 per-element ops matching jnp, for the exact-recheck score exponent
__device__ __forceinline__ double score_exponent(float cv, float middle, float amplitude) {
  float d  = (1.0f - cv) / 0.2f;
  float dc = (d - middle) / amplitude;
  return (double)dc * (-(1.0 / 0.005));
}

// order-preserving f32 <-> u32 encode for atomic min/max
__device__ __forceinline__ unsigned enc_f32(float f) {
  unsigned u = __float_as_uint(f);
  return (u & 0x80000000u) ? ~u : (u | 0x80000000u);
}
__device__ __forceinline__ float dec_f32(unsigned e) {
  unsigned u = (e & 0x80000000u) ? (e & 0x7FFFFFFFu) : ~e;
  return __uint_as_float(u);
}

// shared scalarization: middle / amplitude / rc from the encoded cos max/min.
// Pure f32 function of (maxenc,minenc) -> identical values in every block.
__device__ __forceinline__ void calc_scal(const unsigned* maxenc, const unsigned* minenc,
                                          float& middle, float& amplitude, float& rc_amp) {
  float cosmax = dec_f32(*maxenc);
  float cosmin = dec_f32(*minenc);
  float mx_d = (1.0f - cosmin) / 0.2f;
  float mn_d = (1.0f - cosmax) / 0.2f;
  middle = (mx_d + mn_d) / 2.0f;
  amplitude = fmaxf(mx_d - middle + 1e-5f, 1e-5f);
  rc_amp = 1.0f / amplitude;
}

// async global->LDS 16B: per-lane gptr, WAVE-UNIFORM lds base, lane lands at +lane*16
#if __has_builtin(__builtin_amdgcn_global_load_lds)
#define HAVE_ASYNC_LDS 1
typedef __attribute__((address_space(3))) unsigned int lds_u32_t;
typedef const __attribute__((address_space(1))) unsigned int glb_u32_t;
__device__ __forceinline__ void async_ld16(const void* g, void* l) {
  __builtin_amdgcn_global_load_lds((glb_u32_t*)g, (lds_u32_t*)l, 16, 0, 0);
}
#else
#define HAVE_ASYNC_LDS 0
#endif

// raw sync primitives for the counted-vmcnt pipeline (T3/T4 template)
#define WAITVM8() asm volatile("s_waitcnt vmcnt(8)" ::: "memory")
#define WAITVM4() asm volatile("s_waitcnt vmcnt(4)" ::: "memory")
#define WAITVM0() asm volatile("s_waitcnt vmcnt(0)" ::: "memory")
#define CFENCE()  asm volatile("" ::: "memory")
#define SBAR()    do { CFENCE(); __builtin_amdgcn_s_barrier(); CFENCE(); } while (0)

// ---------- kernels ----------

__global__ __launch_bounds__(1024) void vq_init_kernel(double* __restrict__ u123,
                                                       double* __restrict__ loss_part,
                                                       unsigned* __restrict__ maxenc,
                                                       unsigned* __restrict__ minenc) {
  int t = threadIdx.x;
  for (int i = t; i < 3 * KCB; i += 1024) u123[i] = 0.0;
  loss_part[t] = 0.0;
  if (t == 0) {
    *maxenc = 0u;
    *minenc = 0xFFFFFFFFu;
  }
}

// L2-normalize rows, emit f32 (used post-GEMM for the precise recheck path)
__global__ __launch_bounds__(128) void vq_normalize_rows(const float* __restrict__ in,
                                                         float* __restrict__ out) {
  int row = blockIdx.x;
  int t = threadIdx.x;
  float v = in[(size_t)row * DDIM + t];
  float s = v * v;
#pragma unroll
  for (int off = 32; off; off >>= 1) s += __shfl_down(s, off, 64);
  __shared__ float red[2];
  if ((t & 63) == 0) red[t >> 6] = s;
  __syncthreads();
  float norm = sqrtf(red[0] + red[1]);
  out[(size_t)row * DDIM + t] = v / fmaxf(norm, 1e-12f);
}

// L2-normalize rows, emit split bf16 planes: v = hi + lo + O(2^-18 v)
__global__ __launch_bounds__(128) void vq_normalize_split(const float* __restrict__ in,
                                                          unsigned short* __restrict__ oh,
                                                          unsigned short* __restrict__ ol) {
  int row = blockIdx.x;
  int t = threadIdx.x;
  float v = in[(size_t)row * DDIM + t];
  float s = v * v;
#pragma unroll
  for (int off = 32; off; off >>= 1) s += __shfl_down(s, off, 64);
  __shared__ float red[2];
  if ((t & 63) == 0) red[t >> 6] = s;
  __syncthreads();
  float norm = sqrtf(red[0] + red[1]);
  float xnv = v / fmaxf(norm, 1e-12f);
  unsigned short h = bf16_rne(xnv);
  float fh = bf16_tof(h);
  unsigned short l = bf16_rne(xnv - fh);  // v - fh exact in f32
  size_t idx = (size_t)row * DDIM + t;
  oh[idx] = h;
  ol[idx] = l;
}

// ---- MFMA GEMM: cos = A·B^T, 2-way bf16 split, m201-ported 8-phase template.
// R5-measured optimum structure.  Structure ledger (totals; per-dispatch
// rocprof cross-run noise is +-25%): R2 fine-split slow; R6 small tile =
// +10us total (real regression); R5 2-phase == R7 merged within total-noise;
// keeping 2-phase.  Phase granularity is PEAKED at 16-MFMA clusters: phase
// 2's ds_reads+stageB overlap phase 1's MFMA cluster across waves.
// Virtual-K: K' = 512, chunk t = 4*ks + j; A-plane = (j<2?hi:lo),
// B-plane = (j&1?lo:hi); t ascending == baseline hh,hl,lh,ll per ks ->
// per-acc accumulation order unchanged -> Cm BIT-IDENTICAL.
// Geometry: BM=BN=256, 8 waves (2M x 4N), wave tile 128x64, acc[8][4].
// LDS ring-4 x (A 16K + B 16K) = 128 KB, 1 block/CU.  Stage = one unit
// (2 x global_load_lds 16B) per phase, targeting K-step t+3 (depth-3,
// ~1300 cyc lookahead > ~900 cyc HBM latency).  Counted waits only at
// K-step boundaries: vmcnt(8) steady (t+2,t+3 in flight), 4/0 at tail;
// never a mid-loop drain (T4).  Raw s_barrier pairs per phase, setprio
// around MFMA clusters (T5).  Read-safety: own vmcnt(N) + block barrier =>
// buf(t+1) staged chip-wide before read.  Overwrite-safety: stage(t+3)
// writes buf[(t-1)&3] whose frag reads retired before t-1's closing barrier.
// Bank conflicts: XOR slot swizzle j' = j ^ ((row>>1)&3), involution
// pre-applied to the per-lane GLOBAL source (LDS dest linear, rule 21) --
// validated 0 conflicts.

__global__ __launch_bounds__(512, 2) void vq_gemm_mfma(const unsigned short* __restrict__ Ah,
                                                       const unsigned short* __restrict__ Al,
                                                       const unsigned short* __restrict__ Bh,
                                                       const unsigned short* __restrict__ Bl,
                                                       float* __restrict__ Cm,
                                                       unsigned* __restrict__ maxenc,
                                                       unsigned* __restrict__ minenc) {
  __shared__ unsigned short Ab[4][8192];  // 4 x 16KB: [256 rows][32 k] swizzled
  __shared__ unsigned short Bb[4][8192];  // 4 x 16KB
  __shared__ float redmx[8], redmn[8];
  int tid = threadIdx.x;
  int lane = tid & 63, wv = tid >> 6;
  int wm = wv >> 2, wn = wv & 3;          // wave tile: rows wm*128, cols wn*64
  int n0 = blockIdx.x * 256;              // x = row-block: consecutive blocks share B panel
  int c0 = blockIdx.y * 256;
  int fr = lane & 15;
  // swizzled 16B slot for frag reads: j' = (lane>>4) ^ ((fr>>1)&3), in shorts
  int swz8 = (((lane >> 4) ^ ((lane >> 1) & 3))) * 8;
  int arow = (wm * 128 + fr) * 32 + swz8;  // shorts into A buffer (+rt*512)
  int brow = (wn * 64 + fr) * 32 + swz8;   // shorts into B buffer (+ct*512)
  // stage source swizzle (involution of the read swizzle), constant per thread
  int srcj8 = (((tid & 3) ^ ((tid >> 3) & 3))) * 8;
  int r0 = tid >> 2;                       // staged row for chunk l=0
  f32x4 acc[8][4] = {};                    // [rt][ct]

  auto stageA = [&](int t) {
    const unsigned short* p = ((t & 3) < 2) ? Ah : Al;
    const unsigned short* g = p + (size_t)(n0 + r0) * DDIM + (t >> 2) * 32 + srcj8;
    unsigned short* lb = &Ab[t & 3][wv * 512];  // wave-uniform; lane at +lane*16B
#if HAVE_ASYNC_LDS
    async_ld16(g, lb);
    async_ld16(g + (size_t)128 * DDIM, lb + 4096);
#else
    *(short8*)(&Ab[t & 3][tid * 8])        = *(const short8*)g;
    *(short8*)(&Ab[t & 3][4096 + tid * 8]) = *(const short8*)(g + (size_t)128 * DDIM);
#endif
  };
  auto stageB = [&](int t) {
    const unsigned short* p = (t & 1) ? Bl : Bh;
    const unsigned short* g = p + (size_t)(c0 + r0) * DDIM + (t >> 2) * 32 + srcj8;
    unsigned short* lb = &Bb[t & 3][wv * 512];
#if HAVE_ASYNC_LDS
    async_ld16(g, lb);
    async_ld16(g + (size_t)128 * DDIM, lb + 4096);
#else
    *(short8*)(&Bb[t & 3][tid * 8])        = *(const short8*)g;
    *(short8*)(&Bb[t & 3][4096 + tid * 8]) = *(const short8*)(g + (size_t)128 * DDIM);
#endif
  };

  // prologue: stage K-steps 0,1,2 (12 vm instr/wave); require step 0 done.
  stageA(0); stageB(0);
  stageA(1); stageB(1);
  stageA(2); stageB(2);
  WAITVM8();
  SBAR();

  short8 af[4], bf[4];
#pragma unroll
  for (int t = 0; t < 16; ++t) {
    const unsigned short* ab = &Ab[t & 3][0];
    const unsigned short* bb = &Bb[t & 3][0];
    // ---------- phase 1: B(ct0-3) + A(rt0-3) frags; stage A-unit of t+3
#pragma unroll
    for (int ct = 0; ct < 4; ++ct) bf[ct] = *(const short8*)(bb + brow + ct * 512);
#pragma unroll
    for (int rt = 0; rt < 4; ++rt) af[rt] = *(const short8*)(ab + arow + rt * 512);
    if (t <= 12) stageA(t + 3);
    SBAR();
    __builtin_amdgcn_s_setprio(1);
#pragma unroll
    for (int rt = 0; rt < 4; ++rt)
#pragma unroll
      for (int ct = 0; ct < 4; ++ct)
        acc[rt][ct] = __builtin_amdgcn_mfma_f32_16x16x32_bf16(af[rt], bf[ct], acc[rt][ct], 0, 0, 0);
    __builtin_amdgcn_s_setprio(0);
    SBAR();
    // ---------- phase 2: A(rt4-7) frags; stage B-unit of t+3
#pragma unroll
    for (int rt = 0; rt < 4; ++rt) af[rt] = *(const short8*)(ab + arow + (rt + 4) * 512);
    if (t <= 12) stageB(t + 3);
    SBAR();
    __builtin_amdgcn_s_setprio(1);
#pragma unroll
    for (int rt = 0; rt < 4; ++rt)
#pragma unroll
      for (int ct = 0; ct < 4; ++ct)
        acc[rt + 4][ct] = __builtin_amdgcn_mfma_f32_16x16x32_bf16(af[rt], bf[ct], acc[rt + 4][ct], 0, 0, 0);
    __builtin_amdgcn_s_setprio(0);
    // K-step boundary: ensure buf (t+1) staged chip-wide before next reads.
    if (t <= 12) WAITVM8();
    else if (t == 13) WAITVM4();
    else if (t == 14) WAITVM0();
    SBAR();
  }

  float mx = -3.402823466e38f, mn = 3.402823466e38f;
  int orow = (lane >> 4) * 4, ocol = lane & 15;
  int rn0 = n0 + wm * 128, rc0 = c0 + wn * 64;
#pragma unroll
  for (int rt = 0; rt < 8; ++rt) {
#pragma unroll
    for (int ct = 0; ct < 4; ++ct) {
#pragma unroll
      for (int r = 0; r < 4; ++r) {
        float v = acc[rt][ct][r];
        mx = fmaxf(mx, v);
        mn = fminf(mn, v);
        Cm[(size_t)(rn0 + rt * 16 + orow + r) * KCB + (rc0 + ct * 16 + ocol)] = v;
      }
    }
  }
#pragma unroll
  for (int off = 32; off; off >>= 1) {
    mx = fmaxf(mx, __shfl_down(mx, off, 64));
    mn = fminf(mn, __shfl_down(mn, off, 64));
  }
  if (lane == 0) { redmx[wv] = mx; redmn[wv] = mn; }
  __syncthreads();
  if (tid == 0) {
#pragma unroll
    for (int w = 1; w < 8; ++w) {
      mx = fmaxf(mx, redmx[w]);
      mn = fminf(mn, redmn[w]);
    }
    mx = fmaxf(mx, redmx[0]);
    mn = fminf(mn, redmn[0]);
    atomicMax(maxenc, enc_f32(mx));
    atomicMin(minenc, enc_f32(mn));
  }
}

// ---- Sinkhorn sweep: wave-per-row, zero per-row barriers, depth-1 prefetch
// (R9-proven: cva/cvb constant-indexed -> registers, no scratch).
// scalarization (middle/amp/rc) computed inline from maxenc/minenc. ----
#define SROWS 32
#define SRPW  8

__global__ __launch_bounds__(256) void vq_sweep(const float* __restrict__ Cm,
                                                const unsigned* __restrict__ maxenc,
                                                const unsigned* __restrict__ minenc,
                                                const double* __restrict__ Rvec,
                                                const double* __restrict__ alpha_p,
                                                double* __restrict__ u_out) {
  int t = threadIdx.x;
  int lane = t & 63, wv = t >> 6;
  int n0 = blockIdx.x * SROWS + wv * SRPW;
  float middle, amp, rc;
  calc_scal(maxenc, minenc, middle, amp, rc);
  bool hasR = (Rvec != nullptr);
  double Rreg[16];
  double ainv = 0.0;
  if (hasR) {
#pragma unroll
    for (int c = 0; c < 4; ++c)
#pragma unroll
      for (int e = 0; e < 4; ++e) Rreg[c * 4 + e] = Rvec[c * 256 + lane * 4 + e];
    ainv = alpha_p[0] * 32768.0;
  }
  double up[16] = {};
  float4 cva[4], cvb[4];
  {
    const float4* row0 = (const float4*)(Cm + (size_t)n0 * KCB);
#pragma unroll
    for (int c = 0; c < 4; ++c) cva[c] = row0[c * 64 + lane];
  }
#pragma unroll 1
  for (int r = 0; r < SRPW; ++r) {
    int rn = (r < SRPW - 1) ? r + 1 : r;
    const float4* rown = (const float4*)(Cm + (size_t)(n0 + rn) * KCB);
#pragma unroll
    for (int c = 0; c < 4; ++c) cvb[c] = rown[c * 64 + lane];
    double e[16];
#pragma unroll
    for (int c = 0; c < 4; ++c) {
      e[c * 4 + 0] = sweep_E(cva[c].x, middle, amp, rc);
      e[c * 4 + 1] = sweep_E(cva[c].y, middle, amp, rc);
      e[c * 4 + 2] = sweep_E(cva[c].z, middle, amp, rc);
      e[c * 4 + 3] = sweep_E(cva[c].w, middle, amp, rc);
    }
    if (hasR) {
      double s = 0.0;
#pragma unroll
      for (int i = 0; i < 16; ++i) s += e[i] * Rreg[i];
#pragma unroll
      for (int off = 1; off < 64; off <<= 1) s += __shfl_xor(s, off, 64);
      double C = 1.0 / (ainv * s);
#pragma unroll
      for (int i = 0; i < 16; ++i) up[i] += e[i] * C;
    } else {
#pragma unroll
      for (int i = 0; i < 16; ++i) up[i] += e[i];
    }
#pragma unroll
    for (int c = 0; c < 4; ++c) cva[c] = cvb[c];
  }
  __shared__ double su[4][KCB];  // 32 KB
#pragma unroll
  for (int c = 0; c < 4; ++c)
#pragma unroll
    for (int e = 0; e < 4; ++e) su[wv][c * 256 + lane * 4 + e] = up[c * 4 + e];
  __syncthreads();
#pragma unroll
  for (int j = 0; j < 4; ++j) {
    int k = (t + ((blockIdx.x + j) & 3) * 256) & (KCB - 1);
    double v = su[0][k] + su[1][k] + su[2][k] + su[3][k];
    atomic_add_f64(&u_out[k], v);
  }
}

// mode 0: also compute alpha = 1/max(sum u, 1e-5); mode 2: also lnR
__global__ __launch_bounds__(1024) void vq_finalize_u(const double* __restrict__ u,
                                                      double* __restrict__ alpha_p,
                                                      double* __restrict__ R,
                                                      double* __restrict__ lnR,
                                                      int mode) {
  int k = threadIdx.x;
  double uk = u[k];
  __shared__ double red[16];
  __shared__ double s_alpha;
  if (mode == 0) {
    double s = uk;
#pragma unroll
    for (int off = 32; off; off >>= 1) s += __shfl_down(s, off, 64);
    if ((k & 63) == 0) red[k >> 6] = s;
    __syncthreads();
    if (k == 0) {
      double s0 = 0.0;
      for (int w = 0; w < 16; ++w) s0 += red[w];
      double a = 1.0 / fmax(s0, 1e-5);
      s_alpha = a;
      alpha_p[0] = a;
    }
    __syncthreads();
  }
  double alpha = (mode == 0) ? s_alpha : alpha_p[0];
  double r = 1.0 / (alpha * 1024.0 * uk);
  R[k] = r;
  if (mode == 2) lnR[k] = log(r);
}

// ---- final pass: wave-per-row; f32 top-2 argmax with exact-recheck, CE loss.
// R4: scratch eliminated (rule #20) -- recheck candidate loop FULLY unrolled
// so sv[] stays register-resident; lnRd[] dropped (rare path loads lnR[k]
// f64 straight from global, same value); recheck dot loads vectorized as
// float4 but ACCUMULATED in the identical ascending-d scalar fmaf order ->
// bit-identical dot, bestk, loss.
// R11 row-pair interleave REVERTED: +12 VGPR dropped occupancy 25->17%,
// cancelling the ILP gain (null on dur, negative on total). ----
#define FRPW 4
#define MARGIN 0.08f
#define LOG2E 1.44269504088896340736f

__global__ __launch_bounds__(256) void vq_final_pass(const float* __restrict__ Cm,
                                                     const float* __restrict__ x,
                                                     const float* __restrict__ cb,
                                                     const float* __restrict__ xn,
                                                     const float* __restrict__ cn,
                                                     const double* __restrict__ lnR,
                                                     const unsigned* __restrict__ maxenc,
                                                     const unsigned* __restrict__ minenc,
                                                     double* __restrict__ loss_part,
                                                     float* __restrict__ out_xq,
                                                     float* __restrict__ out_idx) {
  int t = threadIdx.x;
  int lane = t & 63, wv = t >> 6;
  int n0 = blockIdx.x * (4 * FRPW) + wv * FRPW;
  float middle, amplitude, rc_amp;
  calc_scal(maxenc, minenc, middle, amplitude, rc_amp);
  float lnRf[16];
#pragma unroll
  for (int c = 0; c < 4; ++c)
#pragma unroll
    for (int e = 0; e < 4; ++e)
      lnRf[c * 4 + e] = (float)lnR[c * 256 + lane * 4 + e];

  double loss_loc = 0.0;
  float4 cva[4], cvb[4];
  {
    const float4* row0 = (const float4*)(Cm + (size_t)n0 * KCB);
#pragma unroll
    for (int c = 0; c < 4; ++c) cva[c] = row0[c * 64 + lane];
  }
#pragma unroll 1
  for (int r = 0; r < FRPW; ++r) {
    int n = n0 + r;
    int rn = (r < FRPW - 1) ? r + 1 : r;
    const float4* rown = (const float4*)(Cm + (size_t)(n0 + rn) * KCB);
#pragma unroll
    for (int c = 0; c < 4; ++c) cvb[c] = rown[c * 64 + lane];

    float lv[16];
    float sv[16];
    float b1 = -3.402823466e38f, b2 = -3.402823466e38f;
    int k1 = 0;
    float lmax = -3.402823466e38f;
#pragma unroll
    for (int c = 0; c < 4; ++c) {
#pragma unroll
      for (int e = 0; e < 4; ++e) {
        float cvv = (e == 0) ? cva[c].x : (e == 1) ? cva[c].y : (e == 2) ? cva[c].z : cva[c].w;
        int k = c * 256 + lane * 4 + e;  // ascending within lane
        float d  = div_mark(1.0f - cvv, 0.2f, 5.0f);
        float dc = div_mark(d - middle, amplitude, rc_amp);
        float s  = fmaf(dc, -200.0f, lnRf[c * 4 + e]);
        sv[c * 4 + e] = s;
        if (s > b1) { b2 = b1; b1 = s; k1 = k; }
        else if (s > b2) b2 = s;
        float l = div_mark(cvv, 0.2f, 5.0f);
        lv[c * 4 + e] = l;
        lmax = fmaxf(lmax, l);
      }
    }
    // butterfly top-2 (tie -> smaller k) + max reduce; all lanes converge
#pragma unroll
    for (int off = 1; off < 64; off <<= 1) {
      float o1 = __shfl_xor(b1, off, 64);
      int ok = __shfl_xor(k1, off, 64);
      float o2 = __shfl_xor(b2, off, 64);
      float om = __shfl_xor(lmax, off, 64);
      float cand2;
      if (o1 > b1 || (o1 == b1 && ok < k1)) { cand2 = fmaxf(b1, o2); b1 = o1; k1 = ok; }
      else cand2 = fmaxf(o1, o2);
      b2 = fmaxf(b2, cand2);
      lmax = fmaxf(lmax, om);
    }
    int bestk = k1;
    if (b1 - b2 < MARGIN) {
      // close call: recheck flagged candidates with exact f32 dot + f64 score.
      // FULL unroll keeps sv[i] register-resident (no scratch); float4 loads
      // with scalar-order accumulation keep the dot bit-identical.
      double pbest = -1.0e308;
      int pk = KCB;
      const float4* xr4 = (const float4*)(xn + (size_t)n * DDIM);
      float thr = b1 - MARGIN;
#pragma unroll
      for (int i = 0; i < 16; ++i) {
        if (sv[i] >= thr) {
          int k = (i >> 2) * 256 + lane * 4 + (i & 3);
          const float4* cr4 = (const float4*)(cn + (size_t)k * DDIM);
          float dot = 0.0f;
#pragma unroll 4
          for (int d = 0; d < DDIM / 4; ++d) {
            float4 xv4 = xr4[d];
            float4 cv4 = cr4[d];
            dot = fmaf(xv4.x, cv4.x, dot);
            dot = fmaf(xv4.y, cv4.y, dot);
            dot = fmaf(xv4.z, cv4.z, dot);
            dot = fmaf(xv4.w, cv4.w, dot);
          }
          double ps = score_exponent(dot, middle, amplitude) + lnR[k];
          if (ps > pbest || (ps == pbest && k < pk)) { pbest = ps; pk = k; }
        }
      }
#pragma unroll
      for (int off = 1; off < 64; off <<= 1) {
        double ob = __shfl_xor(pbest, off, 64);
        int ok = __shfl_xor(pk, off, 64);
        if (ob > pbest || (ob == pbest && ok < pk)) { pbest = ob; pk = ok; }
      }
      bestk = pk;
    }
    // sum exp (f32, fused exp2) + extract l[bestk]
    float se = 0.0f;
    float lb = 0.0f;
#pragma unroll
    for (int c = 0; c < 4; ++c) {
#pragma unroll
      for (int e = 0; e < 4; ++e) {
        int k = c * 256 + lane * 4 + e;
        se += hw_exp2((lv[c * 4 + e] - lmax) * LOG2E);
        if (k == bestk) lb = lv[c * 4 + e];
      }
    }
#pragma unroll
    for (int off = 1; off < 64; off <<= 1) {
      se += __shfl_xor(se, off, 64);
      lb += __shfl_xor(lb, off, 64);  // exactly one lane nonzero
    }
    loss_loc += (double)(-(lb - lmax - logf(se)));
    if (lane == 0) out_idx[n] = (float)bestk;
    float2 xv = *(const float2*)&x[(size_t)n * DDIM + lane * 2];
    float2 cbv = *(const float2*)&cb[(size_t)bestk * DDIM + lane * 2];
    float2 o;
    o.x = xv.x + (cbv.x - xv.x);
    o.y = xv.y + (cbv.y - xv.y);
    *(float2*)&out_xq[(size_t)n * DDIM + lane * 2] = o;
#pragma unroll
    for (int c = 0; c < 4; ++c) cva[c] = cvb[c];
  }
  if (lane == 0) atomic_add_f64(&loss_part[(blockIdx.x * 4 + wv) & (KCB - 1)], loss_loc);
}

__global__ __launch_bounds__(1024) void vq_loss_div(const double* __restrict__ lp,
                                                    float* __restrict__ out_loss) {
  int t = threadIdx.x;
  double s = lp[t];
#pragma unroll
  for (int off = 32; off; off >>= 1) s += __shfl_down(s, off, 64);
  __shared__ double red[16];
  if ((t & 63) == 0) red[t >> 6] = s;
  __syncthreads();
  if (t == 0) {
    double tot = 0.0;
    for (int w = 0; w < 16; ++w) tot += red[w];
    out_loss[0] = (float)(tot / 32768.0);
  }
}

// ---------- launch ----------

extern "C" void kernel_launch(void* const* d_in, const int* in_sizes, int n_in,
                              void* d_out, int out_size, void* d_ws, size_t ws_size,
                              hipStream_t stream) {
  const float* x  = (const float*)d_in[0];
  const float* cb = (const float*)d_in[1];
  float* out = (float*)d_out;
  float* out_xq   = out;
  float* out_loss = out + (size_t)NPTS * DDIM;
  float* out_idx  = out + (size_t)NPTS * DDIM + 1;

  // workspace layout (~144.6 MB):
  // [0, 16.5MB): phase 1 = bf16 planes (xh 8M, xl 8M, ch 256K, cl 256K)
  //              phase 2 (post-GEMM) = xn f32 16M, cn f32 512K  (overlay)
  char* w = (char*)d_ws;
  unsigned short* xh = (unsigned short*)w;                         // N*D bf16
  unsigned short* xl = xh + (size_t)NPTS * DDIM;                   // N*D bf16
  unsigned short* ch = xl + (size_t)NPTS * DDIM;                   // K*D bf16
  unsigned short* cl = ch + (size_t)KCB * DDIM;                    // K*D bf16
  float* xn = (float*)w;                                           // N*D f32 (overlay)
  float* cn = xn + (size_t)NPTS * DDIM;                            // K*D f32 (overlay)
  float* cosm = (float*)(w + (size_t)16896 * 1024);                // N*K f32 at +16.5MB
  double* u1  = (double*)(cosm + (size_t)NPTS * KCB);
  double* u2  = u1 + KCB;
  double* u3  = u2 + KCB;
  double* R   = u3 + KCB;
  double* lnR = R + KCB;
  double* loss_part = lnR + KCB;                   // 1024
  double* alpha_p   = loss_part + KCB;
  unsigned* maxenc = (unsigned*)(alpha_p + 1);
  unsigned* minenc = maxenc + 1;

  vq_init_kernel<<<1, 1024, 0, stream>>>(u1, loss_part, maxenc, minenc);

  // phase 1: split-normalized bf16 planes -> MFMA GEMM (8-phase template, R5)
  vq_normalize_split<<<NPTS, 128, 0, stream>>>(x, xh, xl);
  vq_normalize_split<<<KCB, 128, 0, stream>>>(cb, ch, cl);
  vq_gemm_mfma<<<dim3(NPTS / 256, KCB / 256), 512, 0, stream>>>(xh, xl, ch, cl, cosm,
                                                                maxenc, minenc);

  // phase 2: f32 normalized copies (overwrite plane region) for the recheck path
  vq_normalize_rows<<<NPTS, 128, 0, stream>>>(x, xn);
  vq_normalize_rows<<<KCB, 128, 0, stream>>>(cb, cn);

  // Sinkhorn: u1 -> R1 ; (v1+u2 fused) -> R2 ; (v2+u3 fused) -> R3, lnR3
  vq_sweep<<<NPTS / SROWS, 256, 0, stream>>>(cosm, maxenc, minenc, nullptr, alpha_p, u1);
  vq_finalize_u<<<1, 1024, 0, stream>>>(u1, alpha_p, R, lnR, 0);
  vq_sweep<<<NPTS / SROWS, 256, 0, stream>>>(cosm, maxenc, minenc, R, alpha_p, u2);
  vq_finalize_u<<<1, 1024, 0, stream>>>(u2, alpha_p, R, lnR, 1);
  vq_sweep<<<NPTS / SROWS, 256, 0, stream>>>(cosm, maxenc, minenc, R, alpha_p, u3);
  vq_finalize_u<<<1, 1024, 0, stream>>>(u3, alpha_p, R, lnR, 2);

  vq_final_pass<<<NPTS / (4 * FRPW), 256, 0, stream>>>(cosm, x, cb, xn, cn, lnR,
                                                       maxenc, minenc,
                                                       loss_part, out_xq, out_idx);
  vq_loss_div<<<1, 1024, 0, stream>>>(loss_part, out_loss);
}